// Round 1
// baseline (881.925 us; speedup 1.0000x reference)
//
#include <hip/hip_runtime.h>

#define HEADS 16
#define SEQL 32
#define HD 64
#define PASTN 32768
#define TOTN 32800
#define NE 1024
#define CHUNK 1024
#define NCHUNK 33   // 32 past chunks + 1 new-key chunk
#define KT 64       // keys per LDS tile
#define LDP 65      // LDS leading-dim pad (65 mod 32 = 1 -> conflict-free)
#define NEGV -10000.0f

// ---------------- kernel 1: qkv = x @ w_attn + b_attn ----------------
// q -> ws [h][s][d]; k,v -> present rows PASTN..PASTN+31
__global__ __launch_bounds__(256) void qkv_kernel(
    const float* __restrict__ x, const float* __restrict__ w,
    const float* __restrict__ b, float* __restrict__ qws,
    float* __restrict__ present)
{
    int idx = blockIdx.x * 256 + threadIdx.x;      // 32*3072 = 98304
    int s = idx / 3072;
    int col = idx - s * 3072;
    float acc = b[col];
    const float* xr = x + s * NE;
    for (int k = 0; k < NE; ++k)
        acc = fmaf(xr[k], w[k * 3072 + col], acc);
    int g = col >> 10;          // 0=q, 1=k, 2=v (1024-aligned groups)
    int e = col & 1023;
    int h = e >> 6, d = e & 63;
    if (g == 0)
        qws[(h * SEQL + s) * HD + d] = acc;
    else
        present[(((g - 1) * HEADS + h) * TOTN + PASTN + s) * HD + d] = acc;
}

// ------- kernel 2: fused cache-copy + flash-decode partials -------
// block = (head h, chunk c). Chunks 0..31: 1024 past keys (copied to
// present while computing). Chunk 32: the 32 new keys (read from present,
// causal-masked).
__global__ __launch_bounds__(256) void attn_partial(
    const float* __restrict__ past, const float* __restrict__ qws,
    float* __restrict__ present, float* __restrict__ opart,
    float* __restrict__ mws, float* __restrict__ lws)
{
    int h = blockIdx.x / NCHUNK;
    int c = blockIdx.x - h * NCHUNK;
    __shared__ float Qs[SEQL][LDP];
    __shared__ float Ks[KT][LDP];
    __shared__ float Vs[KT][LDP];
    __shared__ float Ss[SEQL][LDP];
    __shared__ float mrow[SEQL], lrow[SEQL], arow[SEQL];
    int tid = threadIdx.x;

    for (int i = tid; i < SEQL * HD; i += 256) {
        int q = i >> 6, d = i & 63;
        Qs[q][d] = qws[(h * SEQL + q) * HD + d];
    }
    if (tid < SEQL) { mrow[tid] = -3e38f; lrow[tid] = 0.f; }
    float acc[8];
#pragma unroll
    for (int j = 0; j < 8; ++j) acc[j] = 0.f;
    int d_own = tid & 63;          // this thread's output dim
    int qbase = (tid >> 6) * 8;    // owns queries qbase..qbase+7
    int nkeys = (c < 32) ? CHUNK : SEQL;
    int kstart = c * CHUNK;        // c==32 -> 32768 (the new keys)
    __syncthreads();

    for (int t0 = 0; t0 < nkeys; t0 += KT) {
        int ntile = min(KT, nkeys - t0);
        // ---- stage K/V tile into LDS; past chunks also copy to present ----
        if (c < 32) {
            for (int i = tid; i < KT * 16; i += 256) {
                int row = i >> 4, d4 = (i & 15) * 4;
                int grow = kstart + t0 + row;
                float4 kk = *(const float4*)&past[(h * PASTN + grow) * HD + d4];
                float4 vv = *(const float4*)&past[((HEADS + h) * PASTN + grow) * HD + d4];
                *(float4*)&present[(h * TOTN + grow) * HD + d4] = kk;
                *(float4*)&present[((HEADS + h) * TOTN + grow) * HD + d4] = vv;
                Ks[row][d4] = kk.x; Ks[row][d4+1] = kk.y; Ks[row][d4+2] = kk.z; Ks[row][d4+3] = kk.w;
                Vs[row][d4] = vv.x; Vs[row][d4+1] = vv.y; Vs[row][d4+2] = vv.z; Vs[row][d4+3] = vv.w;
            }
        } else {
            for (int i = tid; i < ntile * 16; i += 256) {
                int row = i >> 4, d4 = (i & 15) * 4;
                int grow = PASTN + t0 + row;
                float4 kk = *(const float4*)&present[(h * TOTN + grow) * HD + d4];
                float4 vv = *(const float4*)&present[((HEADS + h) * TOTN + grow) * HD + d4];
                Ks[row][d4] = kk.x; Ks[row][d4+1] = kk.y; Ks[row][d4+2] = kk.z; Ks[row][d4+3] = kk.w;
                Vs[row][d4] = vv.x; Vs[row][d4+1] = vv.y; Vs[row][d4+2] = vv.z; Vs[row][d4+3] = vv.w;
            }
        }
        __syncthreads();
        // ---- scores: 32 q x ntile keys ----
        for (int i = tid; i < SEQL * KT; i += 256) {
            int q = i >> 6, t = i & 63;
            if (t < ntile) {
                float s = 0.f;
#pragma unroll
                for (int d = 0; d < HD; ++d)
                    s = fmaf(Qs[q][d], Ks[t][d], s);
                s *= 0.125f;                       // 1/sqrt(64)
                if (c == 32 && (t0 + t) > q) s = NEGV;  // causal mask on new keys
                Ss[q][t] = s;
            }
        }
        __syncthreads();
        // ---- online softmax (one thread per query row) ----
        if (tid < SEQL) {
            int q = tid;
            float mt = -3e38f;
            for (int t = 0; t < ntile; ++t) mt = fmaxf(mt, Ss[q][t]);
            float mnew = fmaxf(mrow[q], mt);
            float alpha = __expf(mrow[q] - mnew);
            float sum = 0.f;
            for (int t = 0; t < ntile; ++t) {
                float p = __expf(Ss[q][t] - mnew);
                Ss[q][t] = p;
                sum += p;
            }
            lrow[q] = lrow[q] * alpha + sum;
            mrow[q] = mnew;
            arow[q] = alpha;
        }
        __syncthreads();
        // ---- PV accumulate ----
#pragma unroll
        for (int j = 0; j < 8; ++j) {
            int q = qbase + j;
            float a = arow[q];
            float s = 0.f;
            for (int t = 0; t < ntile; ++t)
                s = fmaf(Ss[q][t], Vs[t][d_own], s);
            acc[j] = acc[j] * a + s;
        }
        __syncthreads();   // protect Ks/Vs/Ss for next tile
    }
    // ---- write partials ----
    if (tid < SEQL) {
        mws[(h * NCHUNK + c) * SEQL + tid] = mrow[tid];
        lws[(h * NCHUNK + c) * SEQL + tid] = lrow[tid];
    }
#pragma unroll
    for (int j = 0; j < 8; ++j) {
        int q = qbase + j;
        opart[((h * NCHUNK + c) * SEQL + q) * HD + d_own] = acc[j];
    }
}

// -------- kernel 3: combine chunk partials, merge heads --------
__global__ __launch_bounds__(64) void attn_reduce(
    const float* __restrict__ opart, const float* __restrict__ mws,
    const float* __restrict__ lws, float* __restrict__ aws)
{
    int h = blockIdx.x >> 5;
    int q = blockIdx.x & 31;
    int d = threadIdx.x;
    float M = -3e38f;
    for (int c = 0; c < NCHUNK; ++c)
        M = fmaxf(M, mws[(h * NCHUNK + c) * SEQL + q]);
    float L = 0.f, o = 0.f;
    for (int c = 0; c < NCHUNK; ++c) {
        float wgt = __expf(mws[(h * NCHUNK + c) * SEQL + q] - M);
        L = fmaf(lws[(h * NCHUNK + c) * SEQL + q], wgt, L);
        o = fmaf(opart[((h * NCHUNK + c) * SEQL + q) * HD + d], wgt, o);
    }
    aws[q * NE + h * HD + d] = o / L;   // merged heads: [s][e]
}

// -------- kernel 4: out = a @ w_proj + b_proj --------
__global__ __launch_bounds__(256) void proj_kernel(
    const float* __restrict__ aws, const float* __restrict__ w,
    const float* __restrict__ b, float* __restrict__ out)
{
    int idx = blockIdx.x * 256 + threadIdx.x;   // 32*1024
    int s = idx >> 10, e = idx & 1023;
    float acc = b[e];
    const float* ar = aws + s * NE;
    for (int k = 0; k < NE; ++k)
        acc = fmaf(ar[k], w[k * NE + e], acc);
    out[idx] = acc;
}

extern "C" void kernel_launch(void* const* d_in, const int* in_sizes, int n_in,
                              void* d_out, int out_size, void* d_ws, size_t ws_size,
                              hipStream_t stream) {
    const float* x      = (const float*)d_in[0];
    const float* past   = (const float*)d_in[1];   // [2,16,32768,64]
    const float* w_attn = (const float*)d_in[2];   // [1024,3072]
    const float* b_attn = (const float*)d_in[3];
    const float* w_proj = (const float*)d_in[4];   // [1024,1024]
    const float* b_proj = (const float*)d_in[5];

    float* out     = (float*)d_out;                 // [32,1024]
    float* present = out + SEQL * NE;               // [2,16,32800,64]

    // workspace layout (floats)
    float* wsf   = (float*)d_ws;
    float* qws   = wsf;                     // 16*32*64     = 32768
    float* aws   = wsf + 32768;             // 32*1024      = 32768
    float* mws   = wsf + 65536;             // 16*33*32     = 16896
    float* lws   = mws + 16896;             // 16896
    float* opart = lws + 16896;             // 16*33*32*64  = 1081344

    qkv_kernel<<<(SEQL * 3072) / 256, 256, 0, stream>>>(x, w_attn, b_attn, qws, present);
    attn_partial<<<HEADS * NCHUNK, 256, 0, stream>>>(past, qws, present, opart, mws, lws);
    attn_reduce<<<HEADS * SEQL, 64, 0, stream>>>(opart, mws, lws, aws);
    proj_kernel<<<(SEQL * NE) / 256, 256, 0, stream>>>(aws, w_proj, b_proj, out);
}